// Round 2
// baseline (2095.756 us; speedup 1.0000x reference)
//
#include <hip/hip_runtime.h>
#include <math.h>

// Actor network, restructured:
//   t=2,3 cell1 updates are dead code (outputs never consumed).
//   cells 2/3/4 fire once with h=c=0  -> no Whh term, no f gate.
//   t=0 cell1 has h=c=0               -> no Whh term, no f gate.
// Pipeline:
//   1. gemm MBIG : [8192,3072] x Wih1^T -> gates_x for t0 (i,g,o) and t1 (i,f,g,o), +bias
//   2. ew_t0     : gates0 -> h1_0, c1_0
//   3. gemm MWHH : h1_0 @ Whh1^T += gates1 (in place)
//   4. ew_t1     : gates1, c1_0 -> h1_1
//   5. gemm MGATE: h1_1 @ Wih2'[i,g,o] + b -> G0 ; ew_gate -> h2
//   6. gemm MGATE: h2 ...  -> h3
//   7. gemm MGATE: h3 ...  -> h4
//   8. gemm MOUT : h4 @ Wout^T + b_out, relu, action = (u < p)

__device__ __forceinline__ float sigf(float x){ return 1.0f/(1.0f+expf(-x)); }

enum { MBIG=0, MWHH=1, MGATE=2, MOUT=3 };

template<int BM,int BN,int BK,int TM,int TN,int MODE>
__global__ __launch_bounds__((BM/TM)*(BN/TN))
void gemm_k(const float* __restrict__ A,   // plain A [M][K]; state for MBIG
            const float* __restrict__ Ag,  // goal for MBIG
            const float* __restrict__ W,   // weight rows, stride K
            const float* __restrict__ bia, // bih / b_out
            const float* __restrict__ bib, // bhh / unused
            const float* __restrict__ X,   // G1 for MWHH ; u for MOUT
            float* __restrict__ C,
            int K)
{
  constexpr int TX = BN/TN, TY = BM/TM, NT = TX*TY;
  constexpr int KQ = BK/4;
  constexpr int NA = (BM*BK)/(NT*4);
  constexpr int NB = (BN*BK)/(NT*4);
  static_assert(NA>=1 && NB>=1, "tile too small");
  __shared__ float As[BK][BM+4];
  __shared__ float Bs[BK][BN+4];

  const int tid   = threadIdx.x;
  const int nbase = blockIdx.x*BN;
  const int mbase = blockIdx.y*BM;

  // skip dead f-gate columns for t=0 rows of the big GEMM
  if (MODE==MBIG && mbase < 4096 && nbase >= 512 && nbase < 1024) return;

  const int tx = tid % TX, ty = tid / TX;

  float acc[TM][TN];
#pragma unroll
  for (int i=0;i<TM;i++)
#pragma unroll
    for (int j=0;j<TN;j++) acc[i][j]=0.f;

  int aml[NA], akq[NA], bnl[NB], bkq[NB];
#pragma unroll
  for (int i=0;i<NA;i++){ int c = tid + i*NT; aml[i]=c/KQ; akq[i]=c%KQ; }
#pragma unroll
  for (int i=0;i<NB;i++){ int c = tid + i*NT; bnl[i]=c/KQ; bkq[i]=c%KQ; }

  const int wb = (MODE==MGATE) ? (nbase + (nbase>=512?512:0)) : nbase;

  auto loadA = [&](int kt, float4* r){
#pragma unroll
    for (int i=0;i<NA;i++){
      int m = mbase + aml[i];
      int k = kt*BK + akq[i]*4;
      if (MODE==MBIG){
        int b = m & 4095, t = m >> 12;
        const float* src = (k < 2048) ? (A  + ((size_t)b*4 + t)*2048 + k)
                                      : (Ag + ((size_t)b*4 + t)*1024 + (k-2048));
        r[i] = *(const float4*)src;
      } else {
        r[i] = *(const float4*)(A + (size_t)m*K + k);
      }
    }
  };
  auto loadB = [&](int kt, float4* r){
#pragma unroll
    for (int i=0;i<NB;i++){
      int n = wb + bnl[i];
      int k = kt*BK + bkq[i]*4;
      r[i] = *(const float4*)(W + (size_t)n*K + k);
    }
  };
  auto stash = [&](float4* a, float4* b){
#pragma unroll
    for (int i=0;i<NA;i++){
      As[akq[i]*4+0][aml[i]] = a[i].x;
      As[akq[i]*4+1][aml[i]] = a[i].y;
      As[akq[i]*4+2][aml[i]] = a[i].z;
      As[akq[i]*4+3][aml[i]] = a[i].w;
    }
#pragma unroll
    for (int i=0;i<NB;i++){
      Bs[bkq[i]*4+0][bnl[i]] = b[i].x;
      Bs[bkq[i]*4+1][bnl[i]] = b[i].y;
      Bs[bkq[i]*4+2][bnl[i]] = b[i].z;
      Bs[bkq[i]*4+3][bnl[i]] = b[i].w;
    }
  };
  auto compute = [&](){
#pragma unroll
    for (int kk=0;kk<BK;kk++){
      float af[TM], bf[TN];
#pragma unroll
      for (int i=0;i<TM;i++) af[i]=As[kk][ty*TM+i];
#pragma unroll
      for (int j=0;j<TN;j++) bf[j]=Bs[kk][tx*TN+j];
#pragma unroll
      for (int i=0;i<TM;i++)
#pragma unroll
        for (int j=0;j<TN;j++) acc[i][j] = fmaf(af[i], bf[j], acc[i][j]);
    }
  };

  const int nk = K/BK;
  float4 ra[NA], rb[NB];
  loadA(0, ra); loadB(0, rb);
  stash(ra, rb);
  __syncthreads();
  for (int kt=1; kt<nk; ++kt){
    float4 na[NA], nb[NB];
    loadA(kt, na); loadB(kt, nb);   // issue early, hide under compute
    compute();
    __syncthreads();
    stash(na, nb);
    __syncthreads();
  }
  compute();

  // -------- epilogue --------
#pragma unroll
  for (int i=0;i<TM;i++){
    int m = mbase + ty*TM + i;
    float vv[TN];
#pragma unroll
    for (int j=0;j<TN;j++){
      int n = nbase + tx*TN + j;
      float v = acc[i][j];
      if (MODE==MBIG)  v += bia[n] + bib[n];
      if (MODE==MGATE){ int wr = n + (n>=512?512:0); v += bia[wr] + bib[wr]; }
      if (MODE==MOUT) { v += bia[n]; v = fmaxf(v, 0.f); }
      vv[j] = v;
    }
    if (MODE==MBIG){
      int b = m & 4095, t = m >> 12;
      float* dst = C + ((size_t)t*4096 + b)*2048 + nbase + tx*TN;
#pragma unroll
      for (int j4=0;j4<TN;j4+=4)
        *(float4*)(dst+j4) = make_float4(vv[j4],vv[j4+1],vv[j4+2],vv[j4+3]);
    } else if (MODE==MWHH){
      size_t off = (size_t)m*2048 + nbase + tx*TN;
#pragma unroll
      for (int j4=0;j4<TN;j4+=4){
        float4 x4 = *(const float4*)(X + off + j4);
        *(float4*)(C + off + j4) =
          make_float4(vv[j4]+x4.x, vv[j4+1]+x4.y, vv[j4+2]+x4.z, vv[j4+3]+x4.w);
      }
    } else if (MODE==MGATE){
      float* dst = C + (size_t)m*1536 + nbase + tx*TN;
#pragma unroll
      for (int j4=0;j4<TN;j4+=4)
        *(float4*)(dst+j4) = make_float4(vv[j4],vv[j4+1],vv[j4+2],vv[j4+3]);
    } else { // MOUT
      size_t off = (size_t)m*512 + nbase + tx*TN;
#pragma unroll
      for (int j=0;j<TN;j++)
        C[off+j] = (X[off+j] < vv[j]) ? 1.0f : 0.0f;
    }
  }
}

// ---------------- elementwise ----------------
// t=0 cell1: c=sig(i)*tanh(g); h=sig(o)*tanh(c); relu both
__global__ void ew_t0(const float* __restrict__ G, float* __restrict__ h, float* __restrict__ c){
  int idx = blockIdx.x*blockDim.x + threadIdx.x;
  int b = idx >> 9, k = idx & 511;
  const float* g = G + (size_t)b*2048;
  float gi = g[k], gg = g[k+1024], go = g[k+1536];
  float cn = sigf(gi)*tanhf(gg);
  float hn = sigf(go)*tanhf(cn);
  h[idx] = fmaxf(hn, 0.f);
  c[idx] = fmaxf(cn, 0.f);
}
// t=1 cell1 (full): c=sig(f)*c_prev+sig(i)*tanh(g); h=relu(sig(o)*tanh(c))
__global__ void ew_t1(const float* __restrict__ G, const float* __restrict__ cp, float* __restrict__ h){
  int idx = blockIdx.x*blockDim.x + threadIdx.x;
  int b = idx >> 9, k = idx & 511;
  const float* g = G + (size_t)b*2048;
  float gi = g[k], gf = g[k+512], gg = g[k+1024], go = g[k+1536];
  float cn = fmaf(sigf(gf), cp[idx], sigf(gi)*tanhf(gg));
  float hn = sigf(go)*tanhf(cn);
  h[idx] = fmaxf(hn, 0.f);
}
// cells 2/3/4 (zero state): gates layout [4096][1536] = i,g,o
__global__ void ew_gate(const float* __restrict__ G, float* __restrict__ h){
  int idx = blockIdx.x*blockDim.x + threadIdx.x;
  int b = idx >> 9, k = idx & 511;
  const float* g = G + (size_t)b*1536;
  float gi = g[k], gg = g[k+512], go = g[k+1024];
  float cn = sigf(gi)*tanhf(gg);
  float hn = sigf(go)*tanhf(cn);
  h[idx] = fmaxf(hn, 0.f);
}

extern "C" void kernel_launch(void* const* d_in, const int* in_sizes, int n_in,
                              void* d_out, int out_size, void* d_ws, size_t ws_size,
                              hipStream_t stream)
{
  const float* state = (const float*)d_in[0];
  const float* goal  = (const float*)d_in[1];
  const float* u     = (const float*)d_in[2];
  const float* Wih1  = (const float*)d_in[3];
  const float* Whh1  = (const float*)d_in[4];
  const float* bih1  = (const float*)d_in[5];
  const float* bhh1  = (const float*)d_in[6];
  const float* Wih2  = (const float*)d_in[7];
  const float* bih2  = (const float*)d_in[9];
  const float* bhh2  = (const float*)d_in[10];
  const float* Wih3  = (const float*)d_in[11];
  const float* bih3  = (const float*)d_in[13];
  const float* bhh3  = (const float*)d_in[14];
  const float* Wih4  = (const float*)d_in[15];
  const float* bih4  = (const float*)d_in[17];
  const float* bhh4  = (const float*)d_in[18];
  const float* Wout  = (const float*)d_in[19];
  const float* bout  = (const float*)d_in[20];

  float* ws = (float*)d_ws;
  float* G0 = ws;                              // 4096*2048 (gates t0, later i/g/o gates)
  float* G1 = ws + (size_t)4096*2048;          // 4096*2048 (gates t1, in-place update)
  float* ha = ws + (size_t)2*4096*2048;        // 4096*512
  float* ca = ha + (size_t)4096*512;
  float* hb = ca + (size_t)4096*512;

  const int EWB = (4096*512)/256;

  // 1. big GEMM over t=0,1 rows (M=8192, N=2048, K=3072), f-gate skipped for t0
  gemm_k<128,128,16,8,8,MBIG><<<dim3(16,64),256,0,stream>>>(
      state, goal, Wih1, bih1, bhh1, nullptr, G0, 3072);
  // 2. t0 elementwise
  ew_t0<<<EWB,256,0,stream>>>(G0, ha, ca);
  // 3. + h1_0 @ Whh1^T into G1 (M=4096,N=2048,K=512)
  gemm_k<128,128,16,8,8,MWHH><<<dim3(16,32),256,0,stream>>>(
      ha, nullptr, Whh1, nullptr, nullptr, G1, G1, 512);
  // 4. t1 elementwise -> h1_1 (hb)
  ew_t1<<<EWB,256,0,stream>>>(G1, ca, hb);
  // 5. cell2 (M=4096,N=1536,K=512)
  gemm_k<64,64,16,4,4,MGATE><<<dim3(24,64),256,0,stream>>>(
      hb, nullptr, Wih2, bih2, bhh2, nullptr, G0, 512);
  ew_gate<<<EWB,256,0,stream>>>(G0, ha);      // -> h2
  // 6. cell3
  gemm_k<64,64,16,4,4,MGATE><<<dim3(24,64),256,0,stream>>>(
      ha, nullptr, Wih3, bih3, bhh3, nullptr, G0, 512);
  ew_gate<<<EWB,256,0,stream>>>(G0, hb);      // -> h3
  // 7. cell4
  gemm_k<64,64,16,4,4,MGATE><<<dim3(24,64),256,0,stream>>>(
      hb, nullptr, Wih4, bih4, bhh4, nullptr, G0, 512);
  ew_gate<<<EWB,256,0,stream>>>(G0, ha);      // -> h4
  // 8. output layer + Bernoulli compare (M=4096,N=512,K=512)
  gemm_k<64,64,16,4,4,MOUT><<<dim3(8,64),256,0,stream>>>(
      ha, nullptr, Wout, bout, nullptr, u, (float*)d_out, 512);
}

// Round 3
// 1030.113 us; speedup vs baseline: 2.0345x; 2.0345x over previous
//
#include <hip/hip_runtime.h>
#include <math.h>

// Actor network. Two paths:
//  NEW (ws >= 152MB): fp32-accurate GEMM on bf16 MFMA via 3-limb/6-product split.
//  OLD (fallback):    round-2 fp32 vector GEMM (verified correct).
//
// Dead-code analysis (both paths):
//   t=2,3 cell1 updates never consumed; cells 2/3/4 fire once with h=c=0
//   (no Whh term, no f gate); t=0 cell1 has h=c=0.

typedef __attribute__((ext_vector_type(8))) short short8;
typedef __attribute__((ext_vector_type(4))) float f32x4;

__device__ __forceinline__ float sigf(float x){ return 1.0f/(1.0f+expf(-x)); }

// ---------- bf16 limb split (RTNE) ----------
__device__ __forceinline__ unsigned short f2bf(float x){
  unsigned u = __float_as_uint(x);
  u += 0x7fffu + ((u>>16)&1u);
  return (unsigned short)(u>>16);
}
__device__ __forceinline__ float bf2f(unsigned short b){
  return __uint_as_float(((unsigned)b)<<16);
}
__device__ __forceinline__ void split3(float x, unsigned short&a0, unsigned short&a1, unsigned short&a2){
  a0 = f2bf(x); float r = x - bf2f(a0);
  a1 = f2bf(r); r -= bf2f(a1);
  a2 = f2bf(r);
}

// =====================================================================
// Weight pre-conversion: fp32 [R][K] row-major -> limb tiles
// layout (shorts): ((ri*(K/32)+ki)*3 + p)*4096 + r*32 + (slot^((r>>1)&3))*8 + j
//   ri=row/128, r=row%128, ki=k/32, slot=(k%32)/8, j=k%8
// REMAP=1 compacts LSTM i/g/o rows out of the 4H weight (drops f).
// =====================================================================
template<int REMAP>
__global__ __launch_bounds__(256) void conv_w(const float* __restrict__ src,
                                              unsigned short* __restrict__ dst,
                                              int R, int K){
  int id = blockIdx.x*256 + threadIdx.x;
  int spr = K>>3;
  int rd = id / spr;
  if (rd >= R) return;
  int ks = (id - rd*spr)<<3;
  int srow = rd; if (REMAP) srow = rd + (rd>=512 ? 512 : 0);
  const float* s = src + (size_t)srow*K + ks;
  float4 t0 = *(const float4*)s, t1 = *(const float4*)(s+4);
  float v[8] = {t0.x,t0.y,t0.z,t0.w,t1.x,t1.y,t1.z,t1.w};
  short8 s0,s1,s2;
#pragma unroll
  for(int j=0;j<8;j++){
    unsigned short x0,x1,x2; split3(v[j],x0,x1,x2);
    s0[j]=(short)x0; s1[j]=(short)x1; s2[j]=(short)x2;
  }
  int ri = rd>>7, r = rd&127, ki = ks>>5, slot=(ks>>3)&3;
  int sl = slot ^ ((r>>1)&3);
  size_t base = (((size_t)ri*(K>>5) + ki)*3)*4096 + (size_t)r*32 + (size_t)sl*8;
  *(short8*)(dst + base)        = s0;
  *(short8*)(dst + base + 4096) = s1;
  *(short8*)(dst + base + 8192) = s2;
}

// =====================================================================
// MFMA GEMM: C[M,N] = A[M,K] @ W[N,K]^T  via 3-limb bf16, 6 products.
// 128x128 tile, BK=32, 256 threads = 4 waves (2x2 of 64x64).
// A: fp32, converted on the fly.  W: pre-tiled limbs.
// =====================================================================
enum { MBIG=0, MWHH=1, MGATE=2, MOUT=3 };

template<int MODE>
__global__ __launch_bounds__(256) void mgemm(
    const float* __restrict__ A, const float* __restrict__ Ag,
    const unsigned short* __restrict__ Wl,
    const float* __restrict__ bia, const float* __restrict__ bib,
    const float* __restrict__ X, float* __restrict__ C, int K)
{
  __shared__ unsigned short lA[3*4096];
  __shared__ unsigned short lB[3*4096];
  const int tid = threadIdx.x;
  const int nbase = blockIdx.x*128, mbase = blockIdx.y*128;
  if (MODE==MBIG && mbase < 4096 && nbase>=512 && nbase<1024) return; // dead f-gate @ t0

  const int l = tid & 63, w = tid >> 6;
  const int wr = w>>1, wc = w&1;
  const int lr = l & 15, lg = l >> 4;

  // constant fragment LDS offsets (shorts); single-buffered so loop-invariant
  int aoff[4][3], boff[4][3];
#pragma unroll
  for (int f=0; f<4; f++){
    int ar = wr*64 + f*16 + lr;
    int br = wc*64 + f*16 + lr;
    int asl = lg ^ ((ar>>1)&3), bsl = lg ^ ((br>>1)&3);
#pragma unroll
    for (int p=0;p<3;p++){
      aoff[f][p] = p*4096 + ar*32 + asl*8;
      boff[f][p] = p*4096 + br*32 + bsl*8;
    }
  }

  f32x4 acc[4][4];
#pragma unroll
  for (int i=0;i<4;i++)
#pragma unroll
    for (int j=0;j<4;j++) acc[i][j] = (f32x4)(0.f);

  const int nk = K >> 5;
  const size_t wtile0 = ((size_t)blockIdx.x * nk) * 3 * 4096;

  for (int kt=0; kt<nk; ++kt){
    // ---- stage B: pre-tiled limb copy (24KB) ----
    const unsigned short* wt = Wl + wtile0 + (size_t)kt*3*4096;
#pragma unroll
    for (int i=0;i<6;i++){
      int o = (tid + i*256)*8;
      *(short8*)&lB[o] = *(const short8*)&wt[o];
    }
    // ---- stage A: fp32 -> 3 limbs (2x 8-elem slots / thread) ----
#pragma unroll
    for (int i=0;i<2;i++){
      int sidx = tid + i*256;
      int r = sidx>>2, slot = sidx&3;
      int k = kt*32 + slot*8;
      const float* src;
      if (MODE==MBIG){
        int tsel = mbase >> 12;               // t in {0,1}, uniform per block
        int b = (mbase & 4095) + r;
        src = (k < 2048) ? (A  + ((size_t)b*4 + tsel)*2048 + k)
                         : (Ag + ((size_t)b*4 + tsel)*1024 + (k-2048));
      } else {
        src = A + (size_t)(mbase + r)*K + k;
      }
      float4 t0 = *(const float4*)src, t1 = *(const float4*)(src+4);
      float v[8] = {t0.x,t0.y,t0.z,t0.w,t1.x,t1.y,t1.z,t1.w};
      short8 s0,s1,s2;
#pragma unroll
      for (int j=0;j<8;j++){
        unsigned short x0,x1,x2; split3(v[j],x0,x1,x2);
        s0[j]=(short)x0; s1[j]=(short)x1; s2[j]=(short)x2;
      }
      int sl = slot ^ ((r>>1)&3);
      int off = r*32 + sl*8;
      *(short8*)&lA[off]        = s0;
      *(short8*)&lA[off+4096]   = s1;
      *(short8*)&lA[off+8192]   = s2;
    }
    __syncthreads();
    // ---- compute: 96 MFMA / wave / K-step ----
    short8 af[4][3];
#pragma unroll
    for (int f=0; f<4; f++)
#pragma unroll
      for (int p=0;p<3;p++) af[f][p] = *(const short8*)&lA[aoff[f][p]];
#pragma unroll
    for (int fn=0; fn<4; fn++){
      short8 b0 = *(const short8*)&lB[boff[fn][0]];
      short8 b1 = *(const short8*)&lB[boff[fn][1]];
      short8 b2 = *(const short8*)&lB[boff[fn][2]];
#pragma unroll
      for (int fm=0; fm<4; fm++){
        f32x4 a = acc[fm][fn];
        a = __builtin_amdgcn_mfma_f32_16x16x32_bf16(af[fm][0], b0, a, 0,0,0);
        a = __builtin_amdgcn_mfma_f32_16x16x32_bf16(af[fm][0], b1, a, 0,0,0);
        a = __builtin_amdgcn_mfma_f32_16x16x32_bf16(af[fm][1], b0, a, 0,0,0);
        a = __builtin_amdgcn_mfma_f32_16x16x32_bf16(af[fm][1], b1, a, 0,0,0);
        a = __builtin_amdgcn_mfma_f32_16x16x32_bf16(af[fm][0], b2, a, 0,0,0);
        a = __builtin_amdgcn_mfma_f32_16x16x32_bf16(af[fm][2], b0, a, 0,0,0);
        acc[fm][fn] = a;
      }
    }
    __syncthreads();
  }

  // ---- epilogue: C row=(lg*4+r within frag), col=lr [HW-verified mapping] ----
#pragma unroll
  for (int fn=0; fn<4; fn++){
    int n = nbase + wc*64 + fn*16 + lr;
    float badd = 0.f;
    if (MODE==MBIG)  badd = bia[n] + bib[n];
    if (MODE==MGATE){ int wrn = n + (n>=512?512:0); badd = bia[wrn]+bib[wrn]; }
    if (MODE==MOUT)  badd = bia[n];
#pragma unroll
    for (int fm=0; fm<4; fm++){
      int m0 = mbase + wr*64 + fm*16 + lg*4;
#pragma unroll
      for (int r=0;r<4;r++){
        int m = m0 + r;
        float v = acc[fm][fn][r] + badd;
        if (MODE==MBIG)       C[(size_t)m*2048 + n] = v;            // gates row m of [8192][2048]
        else if (MODE==MWHH)  C[(size_t)m*2048 + n] = v + X[(size_t)m*2048 + n];
        else if (MODE==MGATE) C[(size_t)m*1536 + n] = v;
        else { v = fmaxf(v,0.f); C[(size_t)m*512 + n] = (X[(size_t)m*512+n] < v) ? 1.f : 0.f; }
      }
    }
  }
}

// ---------------- elementwise (fp32, shared by both paths) ----------------
__global__ void ew_t0(const float* __restrict__ G, float* __restrict__ h, float* __restrict__ c){
  int idx = blockIdx.x*blockDim.x + threadIdx.x;
  int b = idx >> 9, k = idx & 511;
  const float* g = G + (size_t)b*2048;
  float gi = g[k], gg = g[k+1024], go = g[k+1536];
  float cn = sigf(gi)*tanhf(gg);
  float hn = sigf(go)*tanhf(cn);
  h[idx] = fmaxf(hn, 0.f);
  c[idx] = fmaxf(cn, 0.f);
}
__global__ void ew_t1(const float* __restrict__ G, const float* __restrict__ cp, float* __restrict__ h){
  int idx = blockIdx.x*blockDim.x + threadIdx.x;
  int b = idx >> 9, k = idx & 511;
  const float* g = G + (size_t)b*2048;
  float gi = g[k], gf = g[k+512], gg = g[k+1024], go = g[k+1536];
  float cn = fmaf(sigf(gf), cp[idx], sigf(gi)*tanhf(gg));
  float hn = sigf(go)*tanhf(cn);
  h[idx] = fmaxf(hn, 0.f);
}
__global__ void ew_gate(const float* __restrict__ G, float* __restrict__ h){
  int idx = blockIdx.x*blockDim.x + threadIdx.x;
  int b = idx >> 9, k = idx & 511;
  const float* g = G + (size_t)b*1536;
  float gi = g[k], gg = g[k+512], go = g[k+1024];
  float cn = sigf(gi)*tanhf(gg);
  float hn = sigf(go)*tanhf(cn);
  h[idx] = fmaxf(hn, 0.f);
}

// =====================================================================
// OLD fp32 vector path (round-2, verified) — fallback if ws too small
// =====================================================================
template<int BM,int BN,int BK,int TM,int TN,int MODE>
__global__ __launch_bounds__((BM/TM)*(BN/TN))
void gemm_k(const float* __restrict__ A, const float* __restrict__ Ag,
            const float* __restrict__ W, const float* __restrict__ bia,
            const float* __restrict__ bib, const float* __restrict__ X,
            float* __restrict__ C, int K)
{
  constexpr int TX = BN/TN, TY = BM/TM, NT = TX*TY;
  constexpr int KQ = BK/4;
  constexpr int NA = (BM*BK)/(NT*4);
  constexpr int NB = (BN*BK)/(NT*4);
  __shared__ float As[BK][BM+4];
  __shared__ float Bs[BK][BN+4];
  const int tid = threadIdx.x;
  const int nbase = blockIdx.x*BN, mbase = blockIdx.y*BM;
  if (MODE==MBIG && mbase < 4096 && nbase >= 512 && nbase < 1024) return;
  const int tx = tid % TX, ty = tid / TX;
  float acc[TM][TN];
#pragma unroll
  for (int i=0;i<TM;i++)
#pragma unroll
    for (int j=0;j<TN;j++) acc[i][j]=0.f;
  int aml[NA], akq[NA], bnl[NB], bkq[NB];
#pragma unroll
  for (int i=0;i<NA;i++){ int c = tid + i*NT; aml[i]=c/KQ; akq[i]=c%KQ; }
#pragma unroll
  for (int i=0;i<NB;i++){ int c = tid + i*NT; bnl[i]=c/KQ; bkq[i]=c%KQ; }
  const int wb = (MODE==MGATE) ? (nbase + (nbase>=512?512:0)) : nbase;
  auto loadA = [&](int kt, float4* r){
#pragma unroll
    for (int i=0;i<NA;i++){
      int m = mbase + aml[i], k = kt*BK + akq[i]*4;
      if (MODE==MBIG){
        int b = m & 4095, t = m >> 12;
        const float* src = (k < 2048) ? (A  + ((size_t)b*4 + t)*2048 + k)
                                      : (Ag + ((size_t)b*4 + t)*1024 + (k-2048));
        r[i] = *(const float4*)src;
      } else r[i] = *(const float4*)(A + (size_t)m*K + k);
    }
  };
  auto loadB = [&](int kt, float4* r){
#pragma unroll
    for (int i=0;i<NB;i++)
      r[i] = *(const float4*)(W + (size_t)(wb + bnl[i])*K + kt*BK + bkq[i]*4);
  };
  auto stash = [&](float4* a, float4* b){
#pragma unroll
    for (int i=0;i<NA;i++){
      As[akq[i]*4+0][aml[i]] = a[i].x; As[akq[i]*4+1][aml[i]] = a[i].y;
      As[akq[i]*4+2][aml[i]] = a[i].z; As[akq[i]*4+3][aml[i]] = a[i].w;
    }
#pragma unroll
    for (int i=0;i<NB;i++){
      Bs[bkq[i]*4+0][bnl[i]] = b[i].x; Bs[bkq[i]*4+1][bnl[i]] = b[i].y;
      Bs[bkq[i]*4+2][bnl[i]] = b[i].z; Bs[bkq[i]*4+3][bnl[i]] = b[i].w;
    }
  };
  auto compute = [&](){
#pragma unroll
    for (int kk=0;kk<BK;kk++){
      float af[TM], bf[TN];
#pragma unroll
      for (int i=0;i<TM;i++) af[i]=As[kk][ty*TM+i];
#pragma unroll
      for (int j=0;j<TN;j++) bf[j]=Bs[kk][tx*TN+j];
#pragma unroll
      for (int i=0;i<TM;i++)
#pragma unroll
        for (int j=0;j<TN;j++) acc[i][j] = fmaf(af[i], bf[j], acc[i][j]);
    }
  };
  const int nk = K/BK;
  float4 ra[NA], rb[NB];
  loadA(0, ra); loadB(0, rb);
  stash(ra, rb);
  __syncthreads();
  for (int kt=1; kt<nk; ++kt){
    float4 na[NA], nb[NB];
    loadA(kt, na); loadB(kt, nb);
    compute();
    __syncthreads();
    stash(na, nb);
    __syncthreads();
  }
  compute();
#pragma unroll
  for (int i=0;i<TM;i++){
    int m = mbase + ty*TM + i;
    float vv[TN];
#pragma unroll
    for (int j=0;j<TN;j++){
      int n = nbase + tx*TN + j;
      float v = acc[i][j];
      if (MODE==MBIG)  v += bia[n] + bib[n];
      if (MODE==MGATE){ int wr2 = n + (n>=512?512:0); v += bia[wr2] + bib[wr2]; }
      if (MODE==MOUT) { v += bia[n]; v = fmaxf(v, 0.f); }
      vv[j] = v;
    }
    if (MODE==MBIG){
      int b = m & 4095, t = m >> 12;
      float* dst = C + ((size_t)t*4096 + b)*2048 + nbase + tx*TN;
#pragma unroll
      for (int j4=0;j4<TN;j4+=4)
        *(float4*)(dst+j4) = make_float4(vv[j4],vv[j4+1],vv[j4+2],vv[j4+3]);
    } else if (MODE==MWHH){
      size_t off = (size_t)m*2048 + nbase + tx*TN;
#pragma unroll
      for (int j4=0;j4<TN;j4+=4){
        float4 x4 = *(const float4*)(X + off + j4);
        *(float4*)(C + off + j4) =
          make_float4(vv[j4]+x4.x, vv[j4+1]+x4.y, vv[j4+2]+x4.z, vv[j4+3]+x4.w);
      }
    } else if (MODE==MGATE){
      float* dst = C + (size_t)m*1536 + nbase + tx*TN;
#pragma unroll
      for (int j4=0;j4<TN;j4+=4)
        *(float4*)(dst+j4) = make_float4(vv[j4],vv[j4+1],vv[j4+2],vv[j4+3]);
    } else {
      size_t off = (size_t)m*512 + nbase + tx*TN;
#pragma unroll
      for (int j=0;j<TN;j++)
        C[off+j] = (X[off+j] < vv[j]) ? 1.0f : 0.0f;
    }
  }
}

extern "C" void kernel_launch(void* const* d_in, const int* in_sizes, int n_in,
                              void* d_out, int out_size, void* d_ws, size_t ws_size,
                              hipStream_t stream)
{
  const float* state = (const float*)d_in[0];
  const float* goal  = (const float*)d_in[1];
  const float* u     = (const float*)d_in[2];
  const float* Wih1  = (const float*)d_in[3];
  const float* Whh1  = (const float*)d_in[4];
  const float* bih1  = (const float*)d_in[5];
  const float* bhh1  = (const float*)d_in[6];
  const float* Wih2  = (const float*)d_in[7];
  const float* bih2  = (const float*)d_in[9];
  const float* bhh2  = (const float*)d_in[10];
  const float* Wih3  = (const float*)d_in[11];
  const float* bih3  = (const float*)d_in[13];
  const float* bhh3  = (const float*)d_in[14];
  const float* Wih4  = (const float*)d_in[15];
  const float* bih4  = (const float*)d_in[17];
  const float* bhh4  = (const float*)d_in[18];
  const float* Wout  = (const float*)d_in[19];
  const float* bout  = (const float*)d_in[20];

  const int EWB = (4096*512)/256;
  float* ws = (float*)d_ws;

  // ---------------- MFMA path workspace ----------------
  const size_t szW1 = (size_t)16*96*3*4096;   // shorts
  const size_t szWh = (size_t)16*16*3*4096;
  const size_t szWg = (size_t)12*16*3*4096;
  const size_t szWo = (size_t)4*16*3*4096;
  const size_t needNew = ((size_t)8192*2048 + (size_t)3*4096*512)*4
                       + (szW1 + szWh + 3*szWg + szWo)*2;   // 152,043,520 B

  if (ws_size >= needNew) {
    float* G  = ws;                               // [8192][2048] gates (t0 rows 0..4095, t1 rows 4096..8191)
    float* G1 = G + (size_t)4096*2048;
    float* ha = G + (size_t)8192*2048;
    float* ca = ha + (size_t)4096*512;
    float* hb = ca + (size_t)4096*512;
    unsigned short* Wl1 = (unsigned short*)(hb + (size_t)4096*512);
    unsigned short* Wlh = Wl1 + szW1;
    unsigned short* Wl2 = Wlh + szWh;
    unsigned short* Wl3 = Wl2 + szWg;
    unsigned short* Wl4 = Wl3 + szWg;
    unsigned short* Wlo = Wl4 + szWg;

    // weight limb conversion (runs every call; ~16 µs, graph-safe)
    conv_w<0><<<3072,256,0,stream>>>(Wih1, Wl1, 2048, 3072);
    conv_w<0><<< 512,256,0,stream>>>(Whh1, Wlh, 2048,  512);
    conv_w<1><<< 384,256,0,stream>>>(Wih2, Wl2, 1536,  512);
    conv_w<1><<< 384,256,0,stream>>>(Wih3, Wl3, 1536,  512);
    conv_w<1><<< 384,256,0,stream>>>(Wih4, Wl4, 1536,  512);
    conv_w<0><<< 128,256,0,stream>>>(Wout, Wlo,  512,  512);

    mgemm<MBIG ><<<dim3(16,64),256,0,stream>>>(state, goal, Wl1, bih1, bhh1, nullptr, G, 3072);
    ew_t0<<<EWB,256,0,stream>>>(G, ha, ca);
    mgemm<MWHH ><<<dim3(16,32),256,0,stream>>>(ha, nullptr, Wlh, nullptr, nullptr, G1, G1, 512);
    ew_t1<<<EWB,256,0,stream>>>(G1, ca, hb);
    mgemm<MGATE><<<dim3(12,32),256,0,stream>>>(hb, nullptr, Wl2, bih2, bhh2, nullptr, G, 512);
    ew_gate<<<EWB,256,0,stream>>>(G, ha);
    mgemm<MGATE><<<dim3(12,32),256,0,stream>>>(ha, nullptr, Wl3, bih3, bhh3, nullptr, G, 512);
    ew_gate<<<EWB,256,0,stream>>>(G, hb);
    mgemm<MGATE><<<dim3(12,32),256,0,stream>>>(hb, nullptr, Wl4, bih4, bhh4, nullptr, G, 512);
    ew_gate<<<EWB,256,0,stream>>>(G, ha);
    mgemm<MOUT ><<<dim3( 4,32),256,0,stream>>>(ha, nullptr, Wlo, bout, nullptr, u, (float*)d_out, 512);
    return;
  }

  // ---------------- fallback: round-2 fp32 vector path ----------------
  float* G0 = ws;
  float* G1 = ws + (size_t)4096*2048;
  float* ha = ws + (size_t)2*4096*2048;
  float* ca = ha + (size_t)4096*512;
  float* hb = ca + (size_t)4096*512;

  gemm_k<128,128,16,8,8,MBIG><<<dim3(16,64),256,0,stream>>>(
      state, goal, Wih1, bih1, bhh1, nullptr, G0, 3072);
  ew_t0<<<EWB,256,0,stream>>>(G0, ha, ca);
  gemm_k<128,128,16,8,8,MWHH><<<dim3(16,32),256,0,stream>>>(
      ha, nullptr, Whh1, nullptr, nullptr, G1, G1, 512);
  ew_t1<<<EWB,256,0,stream>>>(G1, ca, hb);
  gemm_k<64,64,16,4,4,MGATE><<<dim3(24,64),256,0,stream>>>(
      hb, nullptr, Wih2, bih2, bhh2, nullptr, G0, 512);
  ew_gate<<<EWB,256,0,stream>>>(G0, ha);
  gemm_k<64,64,16,4,4,MGATE><<<dim3(24,64),256,0,stream>>>(
      ha, nullptr, Wih3, bih3, bhh3, nullptr, G0, 512);
  ew_gate<<<EWB,256,0,stream>>>(G0, hb);
  gemm_k<64,64,16,4,4,MGATE><<<dim3(24,64),256,0,stream>>>(
      hb, nullptr, Wih4, bih4, bhh4, nullptr, G0, 512);
  ew_gate<<<EWB,256,0,stream>>>(G0, ha);
  gemm_k<64,64,16,4,4,MOUT><<<dim3(8,64),256,0,stream>>>(
      ha, nullptr, Wout, bout, nullptr, u, (float*)d_out, 512);
}